// Round 5
// baseline (443.462 us; speedup 1.0000x reference)
//
#include <hip/hip_runtime.h>

// Problem: x [B=256,1,512,512] f32; weights [512,4,1]; biases [512,1].
// out[b,i] = relu( dot(ring_means(b,i,0..3), weights[i,:,0]) + biases[i] )
// ring per corner at (r,c): tl max(r,c), tr max(r,511-c), bl max(511-r,c),
// br max(511-r,511-c).
//
// R1-R4 lesson: plain per-lane global loads plateau at ~1 TB/s regardless of
// inner-loop structure (VALU 12%, BW 11%, all pipes idle) -> suspected per-CU
// vector-load return-path queueing. v6: fetch via global_load_lds DMA staging
// (double-buffered 8-row tiles), compute from LDS, + chunk permutation to
// decorrelate DRAM address streams across blocks.

#define HH 512
#define WW 512
#define NRING 512
#define NB (4 * NRING)   // bins per image: [corner][ring]

struct ShmMain { float tile[2][8][WW]; };                    // 32 KiB
struct ShmEpi  { float sc[4][64][17]; float bins[NB]; };     // 25.6 KiB

// grid: B*8 blocks of 256 threads (4 waves). Block = (image b, 64-row chunk).
// Tile t (8 rows) staged to LDS; wave w computes tile rows w and w+4.
template<bool PARTIALS>
__global__ __launch_bounds__(256)
void ring_sum_kernel(const float* __restrict__ x, float* __restrict__ ws) {
    __shared__ union { ShmMain m; ShmEpi e; } shm;
    const int tid  = threadIdx.x;
    const int lane = tid & 63;
    const int wave = tid >> 6;
    const int idx   = blockIdx.x;
    const int b     = idx >> 3;
    const int chunk = (idx + (idx >> 3)) & 7;   // permuted: bijective per image

    // col bins: ring = c (TL,BL) or 511-c (TR,BR); lane owns cols cA..+3, cB..+3
    float vTL[8] = {0,0,0,0,0,0,0,0};
    float vTR[8] = {0,0,0,0,0,0,0,0};
    float vBL[8] = {0,0,0,0,0,0,0,0};
    float vBR[8] = {0,0,0,0,0,0,0,0};
    // row bins: j = 2*t + jj  <->  tile-local row = wave + 4*jj of tile t
    float rTL[16], rTR[16], rBL[16], rBR[16];
    #pragma unroll
    for (int k = 0; k < 16; ++k) { rTL[k]=0.f; rTR[k]=0.f; rBL[k]=0.f; rBR[k]=0.f; }

    const size_t imgF = (size_t)b * (HH * WW);
    const int cA = 4 * lane;
    const int cB = 256 + 4 * lane;
    const bool top = (chunk < 4);               // block-uniform

    // stage tile tt (8 rows = 16 KiB) into buffer bufi: 4 rounds x 16 B/thread
#define STAGE(bufi, tt)                                                        \
    do {                                                                       \
        const float* gsrc = x + imgF + (size_t)(chunk * 64 + (tt) * 8) * WW    \
                              + tid * 4;                                       \
        float* ldst = &shm.m.tile[bufi][0][0] + tid * 4;                       \
        _Pragma("unroll")                                                      \
        for (int rr = 0; rr < 4; ++rr)                                         \
            __builtin_amdgcn_global_load_lds(                                  \
                (const __attribute__((address_space(1))) void*)(gsrc + rr * 1024), \
                (__attribute__((address_space(3))) void*)(ldst + rr * 1024),   \
                16, 0, 0);                                                     \
    } while (0)

    STAGE(0, 0);
    __syncthreads();   // drains vmcnt(0): tile 0 resident

    #pragma unroll
    for (int t = 0; t < 8; ++t) {
        if (t < 7) STAGE((t + 1) & 1, t + 1);
        const int bufi = t & 1;
        const int r0c = chunk * 64 + t * 8;
        #pragma unroll
        for (int jj = 0; jj < 2; ++jj) {
            const int kloc = wave + 4 * jj;       // tile-local row
            const int r = r0c + kloc;
            const int s = 511 - r;
            const int j = 2 * t + jj;             // row-bin index (static)
            const float4 a  = *(const float4*)&shm.m.tile[bufi][kloc][cA];
            const float4 bb = *(const float4*)&shm.m.tile[bufi][kloc][cB];
            if (top) {
                #pragma unroll
                for (int e = 0; e < 4; ++e) {     // group A: c < 256
                    float v = (&a.x)[e]; int c = cA + e;
                    rBL[j] += v;                  // bl uniform (ring 511-r)
                    vTR[e] += v;                  // tr col bin (ring 511-c)
                    float sel  = (c <= r) ? v : 0.f; rTL[j] += sel;  vTL[e] += v - sel;
                    float sel2 = (c >= r) ? v : 0.f; rBR[j] += sel2; vBR[e] += v - sel2;
                }
                #pragma unroll
                for (int e = 0; e < 4; ++e) {     // group B: c >= 256
                    float v = (&bb.x)[e]; int c = cB + e;
                    rBR[j] += v;                  // br uniform
                    vTL[4 + e] += v;              // tl col bin (ring c)
                    float sel  = (c >= s) ? v : 0.f; rTR[j] += sel;  vTR[4 + e] += v - sel;
                    float sel2 = (c <= s) ? v : 0.f; rBL[j] += sel2; vBL[4 + e] += v - sel2;
                }
            } else {
                #pragma unroll
                for (int e = 0; e < 4; ++e) {     // group A
                    float v = (&a.x)[e]; int c = cA + e;
                    rTL[j] += v;                  // tl uniform (ring r)
                    vBR[e] += v;                  // br col bin (ring 511-c)
                    float sel  = (c >= s) ? v : 0.f; rTR[j] += sel;  vTR[e] += v - sel;
                    float sel2 = (c <= s) ? v : 0.f; rBL[j] += sel2; vBL[e] += v - sel2;
                }
                #pragma unroll
                for (int e = 0; e < 4; ++e) {     // group B
                    float v = (&bb.x)[e]; int c = cB + e;
                    rTR[j] += v;                  // tr uniform
                    vBL[4 + e] += v;              // bl col bin (ring c)
                    float sel  = (c <= r) ? v : 0.f; rTL[j] += sel;  vTL[4 + e] += v - sel;
                    float sel2 = (c >= r) ? v : 0.f; rBR[j] += sel2; vBR[4 + e] += v - sel2;
                }
            }
        }
        __syncthreads();   // drains stage(t+1); all waves done with buf t&1
    }
#undef STAGE

    // ---- epilogue (union switches to sc+bins; tiles dead after barrier) ----
    for (int t2 = tid; t2 < NB; t2 += 256) shm.e.bins[t2] = 0.f;
    __syncthreads();

    // reduce each row-bin array across the wave's 64 lanes via LDS transpose;
    // row-bin j of wave w  <->  chunk-local row 8*(j>>1) + w + 4*(j&1)
    const int q  = lane >> 4;
    const int kk = lane & 15;
    const int rl = 8 * (kk >> 1) + wave + 4 * (kk & 1);  // chunk-local row
#define REDUCE_CORNER(ARR, CIDX, RING)                                         \
    {                                                                          \
        _Pragma("unroll")                                                      \
        for (int j2 = 0; j2 < 16; ++j2) shm.e.sc[wave][lane][j2] = ARR[j2];    \
        __syncthreads();                                                       \
        float acc = 0.f;                                                       \
        _Pragma("unroll")                                                      \
        for (int l = 0; l < 16; ++l) acc += shm.e.sc[wave][q * 16 + l][kk];    \
        acc += __shfl_down(acc, 32);                                           \
        acc += __shfl_down(acc, 16);                                           \
        if (lane < 16) atomicAdd(&shm.e.bins[(CIDX) * NRING + (RING)], acc);   \
        __syncthreads();                                                       \
    }
    REDUCE_CORNER(rTL, 0, chunk * 64 + rl)
    REDUCE_CORNER(rTR, 1, chunk * 64 + rl)
    REDUCE_CORNER(rBL, 2, 511 - (chunk * 64 + rl))
    REDUCE_CORNER(rBR, 3, 511 - (chunk * 64 + rl))
#undef REDUCE_CORNER

    // flush per-lane col bins (ring depends only on owned column c)
    #pragma unroll
    for (int e = 0; e < 8; ++e) {
        int c = (e < 4) ? (cA + e) : (cB + e - 4);
        atomicAdd(&shm.e.bins[0 * NRING + c],         vTL[e]);
        atomicAdd(&shm.e.bins[1 * NRING + (511 - c)], vTR[e]);
        atomicAdd(&shm.e.bins[2 * NRING + c],         vBL[e]);
        atomicAdd(&shm.e.bins[3 * NRING + (511 - c)], vBR[e]);
    }
    __syncthreads();

    if (PARTIALS) {
        float* outp = ws + ((size_t)b * 8 + chunk) * NB;
        for (int t2 = tid; t2 < NB; t2 += 256) outp[t2] = shm.e.bins[t2];
    } else {
        float* outp = ws + (size_t)b * NB;
        for (int t2 = tid; t2 < NB; t2 += 256) atomicAdd(&outp[t2], shm.e.bins[t2]);
    }
}

// ------------- Kernel 2: fold partials + mean + linear + bias + relu -------
__global__ __launch_bounds__(512)
void linear_kernel(const float* __restrict__ ws, const float* __restrict__ wts,
                   const float* __restrict__ bias, float* __restrict__ out,
                   int nparts) {
    const int b = blockIdx.x;
    const int i = threadIdx.x;   // ring index
    const float* base = ws + (size_t)b * nparts * NB;
    float s0 = 0.f, s1 = 0.f, s2 = 0.f, s3 = 0.f;
    for (int p = 0; p < nparts; ++p) {
        const float* pb = base + (size_t)p * NB;
        s0 += pb[0 * NRING + i];
        s1 += pb[1 * NRING + i];
        s2 += pb[2 * NRING + i];
        s3 += pb[3 * NRING + i];
    }
    float4 w  = ((const float4*)wts)[i];          // weights[i][0..3][0]
    float inv = 1.0f / (float)(2 * i + 1);
    float val = (s0 * w.x + s1 * w.y + s2 * w.z + s3 * w.w) * inv + bias[i];
    out[b * NRING + i] = fmaxf(val, 0.0f);
}

extern "C" void kernel_launch(void* const* d_in, const int* in_sizes, int n_in,
                              void* d_out, int out_size, void* d_ws, size_t ws_size,
                              hipStream_t stream) {
    const float* x    = (const float*)d_in[0];
    const float* wts  = (const float*)d_in[1];
    const float* bias = (const float*)d_in[2];
    float* out = (float*)d_out;

    const int B = in_sizes[0] / (HH * WW);   // 256
    float* ws = (float*)d_ws;

    const size_t need = (size_t)B * 8 * NB * sizeof(float);   // 16 MiB
    if (ws_size >= need) {
        ring_sum_kernel<true><<<dim3(B * 8), dim3(256), 0, stream>>>(x, ws);
        linear_kernel<<<dim3(B), dim3(512), 0, stream>>>(ws, wts, bias, out, 8);
    } else {
        hipMemsetAsync(ws, 0, (size_t)B * NB * sizeof(float), stream);
        ring_sum_kernel<false><<<dim3(B * 8), dim3(256), 0, stream>>>(x, ws);
        linear_kernel<<<dim3(B), dim3(512), 0, stream>>>(ws, wts, bias, out, 1);
    }
}

// Round 6
// 441.074 us; speedup vs baseline: 1.0054x; 1.0054x over previous
//
#include <hip/hip_runtime.h>

// Problem: x [B=256,1,512,512] f32; weights [512,4,1]; biases [512,1].
// out[b,i] = relu( dot(ring_means(b,i,0..3), weights[i,:,0]) + biases[i] )
// ring per corner at (r,c): tl max(r,c), tr max(r,511-c), bl max(511-r,c),
// br max(511-r,511-c).
//
// R5 lesson: __syncthreads() after global_load_lds = s_waitcnt vmcnt(0) +
// barrier -> the "prefetch" was drained in the same barrier that published
// it; blocks ran lockstep {issue 16KB, full drain, tiny compute} rounds.
// v7 (T3+T4): 4 tile buffers, 3-ahead prefetch, counted vmcnt(8) + RAW
// s_barrier in the main loop (never drain), stage-after-barrier for buffer
// reuse safety. Epilogue (LDS transpose reduce + col-bin flush + partials)
// unchanged.

#define HH 512
#define WW 512
#define NRING 512
#define NB (4 * NRING)   // bins per image: [corner][ring]

struct ShmMain { float tile[4][8][WW]; };                    // 64 KiB
struct ShmEpi  { float sc[4][64][17]; float bins[NB]; };     // 25.6 KiB

#define WAITV(n) asm volatile("s_waitcnt vmcnt(" #n ")" ::: "memory")

// grid: B*8 blocks of 256 threads (4 waves). Block = (image b, 64-row chunk).
// Tile t (8 rows, 16 KiB) staged to LDS buffer t%4; wave w computes tile
// rows w and w+4.
template<bool PARTIALS>
__global__ __launch_bounds__(256)
void ring_sum_kernel(const float* __restrict__ x, float* __restrict__ ws) {
    __shared__ union { ShmMain m; ShmEpi e; } shm;
    const int tid  = threadIdx.x;
    const int lane = tid & 63;
    const int wave = tid >> 6;
    const int idx   = blockIdx.x;
    const int b     = idx >> 3;
    const int chunk = (idx + (idx >> 3)) & 7;   // permuted: bijective per image

    // col bins: ring = c (TL,BL) or 511-c (TR,BR); lane owns cols cA..+3, cB..+3
    float vTL[8] = {0,0,0,0,0,0,0,0};
    float vTR[8] = {0,0,0,0,0,0,0,0};
    float vBL[8] = {0,0,0,0,0,0,0,0};
    float vBR[8] = {0,0,0,0,0,0,0,0};
    // row bins: j = 2*t + jj  <->  tile-local row = wave + 4*jj of tile t
    float rTL[16], rTR[16], rBL[16], rBR[16];
    #pragma unroll
    for (int k = 0; k < 16; ++k) { rTL[k]=0.f; rTR[k]=0.f; rBL[k]=0.f; rBR[k]=0.f; }

    const size_t imgF = (size_t)b * (HH * WW);
    const int cA = 4 * lane;
    const int cB = 256 + 4 * lane;
    const bool top = (chunk < 4);               // block-uniform

    // stage tile tt (8 rows = 16 KiB) into buffer bufi: 4 DMA instrs/wave
#define STAGE(bufi, tt)                                                        \
    do {                                                                       \
        const float* gsrc = x + imgF + (size_t)(chunk * 64 + (tt) * 8) * WW    \
                              + tid * 4;                                       \
        float* ldst = &shm.m.tile[bufi][0][0] + tid * 4;                       \
        _Pragma("unroll")                                                      \
        for (int rr = 0; rr < 4; ++rr)                                         \
            __builtin_amdgcn_global_load_lds(                                  \
                (const __attribute__((address_space(1))) void*)(gsrc + rr * 1024), \
                (__attribute__((address_space(3))) void*)(ldst + rr * 1024),   \
                16, 0, 0);                                                     \
    } while (0)

    // prologue: 3 tiles in flight (12 DMA instrs/wave outstanding)
    STAGE(0, 0);
    STAGE(1, 1);
    STAGE(2, 2);

    #pragma unroll
    for (int t = 0; t < 8; ++t) {
        // tile t's 4 DMAs (per wave) are the oldest; leave the rest in flight
        if (t <= 5)      WAITV(8);
        else if (t == 6) WAITV(4);
        else             WAITV(0);
        __builtin_amdgcn_sched_barrier(0);
        __builtin_amdgcn_s_barrier();          // raw: no implicit vmcnt drain
        __builtin_amdgcn_sched_barrier(0);
        // all waves passed => compute(t-1) done => buffer (t-1)%4 free
        if (t < 5) STAGE((t + 3) & 3, t + 3);

        const int bufi = t & 3;
        const int r0c = chunk * 64 + t * 8;
        #pragma unroll
        for (int jj = 0; jj < 2; ++jj) {
            const int kloc = wave + 4 * jj;       // tile-local row
            const int r = r0c + kloc;
            const int s = 511 - r;
            const int j = 2 * t + jj;             // row-bin index (static)
            const float4 a  = *(const float4*)&shm.m.tile[bufi][kloc][cA];
            const float4 bb = *(const float4*)&shm.m.tile[bufi][kloc][cB];
            if (top) {
                #pragma unroll
                for (int e = 0; e < 4; ++e) {     // group A: c < 256
                    float v = (&a.x)[e]; int c = cA + e;
                    rBL[j] += v;                  // bl uniform (ring 511-r)
                    vTR[e] += v;                  // tr col bin (ring 511-c)
                    float sel  = (c <= r) ? v : 0.f; rTL[j] += sel;  vTL[e] += v - sel;
                    float sel2 = (c >= r) ? v : 0.f; rBR[j] += sel2; vBR[e] += v - sel2;
                }
                #pragma unroll
                for (int e = 0; e < 4; ++e) {     // group B: c >= 256
                    float v = (&bb.x)[e]; int c = cB + e;
                    rBR[j] += v;                  // br uniform
                    vTL[4 + e] += v;              // tl col bin (ring c)
                    float sel  = (c >= s) ? v : 0.f; rTR[j] += sel;  vTR[4 + e] += v - sel;
                    float sel2 = (c <= s) ? v : 0.f; rBL[j] += sel2; vBL[4 + e] += v - sel2;
                }
            } else {
                #pragma unroll
                for (int e = 0; e < 4; ++e) {     // group A
                    float v = (&a.x)[e]; int c = cA + e;
                    rTL[j] += v;                  // tl uniform (ring r)
                    vBR[e] += v;                  // br col bin (ring 511-c)
                    float sel  = (c >= s) ? v : 0.f; rTR[j] += sel;  vTR[e] += v - sel;
                    float sel2 = (c <= s) ? v : 0.f; rBL[j] += sel2; vBL[e] += v - sel2;
                }
                #pragma unroll
                for (int e = 0; e < 4; ++e) {     // group B
                    float v = (&bb.x)[e]; int c = cB + e;
                    rTR[j] += v;                  // tr uniform
                    vBL[4 + e] += v;              // bl col bin (ring c)
                    float sel  = (c <= r) ? v : 0.f; rTL[j] += sel;  vTL[4 + e] += v - sel;
                    float sel2 = (c >= r) ? v : 0.f; rBR[j] += sel2; vBR[4 + e] += v - sel2;
                }
            }
        }
        // no barrier here: next iter's barrier (after its wait) protects
        // buffer reuse, and stage of t+3 happens after that barrier.
    }
#undef STAGE

    __syncthreads();   // all waves done reading tiles; vmcnt already 0

    // ---- epilogue (union switches to sc+bins) ----
    for (int t2 = tid; t2 < NB; t2 += 256) shm.e.bins[t2] = 0.f;
    __syncthreads();

    // reduce each row-bin array across the wave's 64 lanes via LDS transpose;
    // row-bin j of wave w  <->  chunk-local row 8*(j>>1) + w + 4*(j&1)
    const int q  = lane >> 4;
    const int kk = lane & 15;
    const int rl = 8 * (kk >> 1) + wave + 4 * (kk & 1);  // chunk-local row
#define REDUCE_CORNER(ARR, CIDX, RING)                                         \
    {                                                                          \
        _Pragma("unroll")                                                      \
        for (int j2 = 0; j2 < 16; ++j2) shm.e.sc[wave][lane][j2] = ARR[j2];    \
        __syncthreads();                                                       \
        float acc = 0.f;                                                       \
        _Pragma("unroll")                                                      \
        for (int l = 0; l < 16; ++l) acc += shm.e.sc[wave][q * 16 + l][kk];    \
        acc += __shfl_down(acc, 32);                                           \
        acc += __shfl_down(acc, 16);                                           \
        if (lane < 16) atomicAdd(&shm.e.bins[(CIDX) * NRING + (RING)], acc);   \
        __syncthreads();                                                       \
    }
    REDUCE_CORNER(rTL, 0, chunk * 64 + rl)
    REDUCE_CORNER(rTR, 1, chunk * 64 + rl)
    REDUCE_CORNER(rBL, 2, 511 - (chunk * 64 + rl))
    REDUCE_CORNER(rBR, 3, 511 - (chunk * 64 + rl))
#undef REDUCE_CORNER

    // flush per-lane col bins (ring depends only on owned column c)
    #pragma unroll
    for (int e = 0; e < 8; ++e) {
        int c = (e < 4) ? (cA + e) : (cB + e - 4);
        atomicAdd(&shm.e.bins[0 * NRING + c],         vTL[e]);
        atomicAdd(&shm.e.bins[1 * NRING + (511 - c)], vTR[e]);
        atomicAdd(&shm.e.bins[2 * NRING + c],         vBL[e]);
        atomicAdd(&shm.e.bins[3 * NRING + (511 - c)], vBR[e]);
    }
    __syncthreads();

    if (PARTIALS) {
        float* outp = ws + ((size_t)b * 8 + chunk) * NB;
        for (int t2 = tid; t2 < NB; t2 += 256) outp[t2] = shm.e.bins[t2];
    } else {
        float* outp = ws + (size_t)b * NB;
        for (int t2 = tid; t2 < NB; t2 += 256) atomicAdd(&outp[t2], shm.e.bins[t2]);
    }
}

// ------------- Kernel 2: fold partials + mean + linear + bias + relu -------
__global__ __launch_bounds__(512)
void linear_kernel(const float* __restrict__ ws, const float* __restrict__ wts,
                   const float* __restrict__ bias, float* __restrict__ out,
                   int nparts) {
    const int b = blockIdx.x;
    const int i = threadIdx.x;   // ring index
    const float* base = ws + (size_t)b * nparts * NB;
    float s0 = 0.f, s1 = 0.f, s2 = 0.f, s3 = 0.f;
    for (int p = 0; p < nparts; ++p) {
        const float* pb = base + (size_t)p * NB;
        s0 += pb[0 * NRING + i];
        s1 += pb[1 * NRING + i];
        s2 += pb[2 * NRING + i];
        s3 += pb[3 * NRING + i];
    }
    float4 w  = ((const float4*)wts)[i];          // weights[i][0..3][0]
    float inv = 1.0f / (float)(2 * i + 1);
    float val = (s0 * w.x + s1 * w.y + s2 * w.z + s3 * w.w) * inv + bias[i];
    out[b * NRING + i] = fmaxf(val, 0.0f);
}

extern "C" void kernel_launch(void* const* d_in, const int* in_sizes, int n_in,
                              void* d_out, int out_size, void* d_ws, size_t ws_size,
                              hipStream_t stream) {
    const float* x    = (const float*)d_in[0];
    const float* wts  = (const float*)d_in[1];
    const float* bias = (const float*)d_in[2];
    float* out = (float*)d_out;

    const int B = in_sizes[0] / (HH * WW);   // 256
    float* ws = (float*)d_ws;

    const size_t need = (size_t)B * 8 * NB * sizeof(float);   // 16 MiB
    if (ws_size >= need) {
        ring_sum_kernel<true><<<dim3(B * 8), dim3(256), 0, stream>>>(x, ws);
        linear_kernel<<<dim3(B), dim3(512), 0, stream>>>(ws, wts, bias, out, 8);
    } else {
        hipMemsetAsync(ws, 0, (size_t)B * NB * sizeof(float), stream);
        ring_sum_kernel<false><<<dim3(B * 8), dim3(256), 0, stream>>>(x, ws);
        linear_kernel<<<dim3(B), dim3(512), 0, stream>>>(ws, wts, bias, out, 1);
    }
}